// Round 8
// baseline (3822.464 us; speedup 1.0000x reference)
//
#include <hip/hip_runtime.h>
#include <stdint.h>

typedef _Float16 f16;
typedef _Float16 f16x8 __attribute__((ext_vector_type(8)));
typedef float f32x4 __attribute__((ext_vector_type(4)));

#define BATCH 256
#define SEQ   128
#define EMB   300
#define HID   1024
#define OUTD  20
#define CAT   1324          // HID + EMB
#define KE    1344          // padded K: 1024 (c) + 320 (x incl bias-1, zero pad)
#define XP    320           // xe row: 300 emb + [300]=1.0 + zeros
#define LSTR  1352          // LDS row stride in f16 (full rows, waves 0,1)
#define LSX   328           // LDS x-part row stride in f16 (320 + 8 pad)
#define BPG   32            // blocks per group (== CUs per XCD)
#define MPG   32            // batch rows per group

__device__ __forceinline__ float sigm(float z)  { return 1.f / (1.f + __expf(-z)); }
__device__ __forceinline__ float tanhf_(float z){ float e = __expf(2.f * z); return 1.f - 2.f / (e + 1.f); }

#define MFMA(a,b,c) __builtin_amdgcn_mfma_f32_16x16x32_f16((a),(b),(c),0,0,0)

#define ALOAD64(p) __hip_atomic_load((const unsigned long long*)(p), \
                                     __ATOMIC_RELAXED, __HIP_MEMORY_SCOPE_AGENT)

// ---------------------------------------------------------------------------
// Weight packing: Wru_e[2048][1344] (rows 0..1023 = W_r|b_r, 1024..2047 = W_u|b_u)
//                 Wc_e[1024][1344], Wp_e[32][1024] (rows >=20 zero)
// ---------------------------------------------------------------------------
__global__ void pack_kernel(const float* __restrict__ Wr, const float* __restrict__ br,
                            const float* __restrict__ Wu, const float* __restrict__ bu,
                            const float* __restrict__ Wc, const float* __restrict__ bc,
                            const float* __restrict__ Wp,
                            f16* __restrict__ Wru_e, f16* __restrict__ Wc_e, f16* __restrict__ Wp_e)
{
    const int NRU = 2048 * KE, NC = 1024 * KE, NP = 32 * HID;
    for (int idx = blockIdx.x * blockDim.x + threadIdx.x; idx < NRU + NC + NP;
         idx += gridDim.x * blockDim.x) {
        if (idx < NRU) {
            int n = idx / KE, k = idx - n * KE;
            const float* Ws = (n < HID) ? Wr : Wu;
            const float* bs = (n < HID) ? br : bu;
            int row = n & (HID - 1);
            float v = (k < CAT) ? Ws[(size_t)row * CAT + k] : ((k == CAT) ? bs[row] : 0.f);
            Wru_e[idx] = (f16)v;
        } else if (idx < NRU + NC) {
            int j = idx - NRU;
            int n = j / KE, k = j - n * KE;
            float v = (k < CAT) ? Wc[(size_t)n * CAT + k] : ((k == CAT) ? bc[n] : 0.f);
            Wc_e[j] = (f16)v;
        } else {
            int j = idx - NRU - NC;
            int n = j / HID, k = j & (HID - 1);
            Wp_e[j] = (n < OUTD) ? (f16)Wp[(size_t)n * HID + k] : (f16)(0.f);
        }
    }
}

// ---------------------------------------------------------------------------
// Embedding gather: xe[t][b][0..319] f16 : emb row, 1.0 at [300], zeros after
// ---------------------------------------------------------------------------
__global__ void gather_kernel(const int* __restrict__ x, const float* __restrict__ emb,
                              f16* __restrict__ xe)
{
    const int TOT = SEQ * BATCH * XP;
    for (int idx = blockIdx.x * blockDim.x + threadIdx.x; idx < TOT;
         idx += gridDim.x * blockDim.x) {
        int e  = idx % XP;
        int rb = idx / XP;            // t*256 + b
        int b  = rb & 255, t = rb >> 8;
        float v;
        if (e < EMB) { int id = x[b * SEQ + t]; v = emb[(size_t)id * EMB + e]; }
        else          v = (e == EMB) ? 1.f : 0.f;
        xe[idx] = (f16)v;
    }
}

__global__ void zero_kernel(uint32_t* __restrict__ c0, int n0, uint32_t* __restrict__ bar, int nb)
{
    for (int i = blockIdx.x * blockDim.x + threadIdx.x; i < n0; i += gridDim.x * blockDim.x)
        c0[i] = 0u;
    if (blockIdx.x == 0)
        for (int i = threadIdx.x; i < nb; i += blockDim.x) bar[i] = 0u;
}

// ---------------------------------------------------------------------------
// Dual-mode relay barrier (unchanged — proven).
// ---------------------------------------------------------------------------
__device__ __forceinline__ void bar_arrive(int* slot, int ep, int fast)
{
    __syncthreads();
    if (threadIdx.x == 0) {
        if (fast) {
            *(volatile int*)slot = ep;
        } else {
            __builtin_amdgcn_fence(__ATOMIC_RELEASE, "agent");
            __hip_atomic_store(slot, ep, __ATOMIC_RELAXED, __HIP_MEMORY_SCOPE_AGENT);
        }
    }
}
__device__ __forceinline__ void bar_check(int* arrg, int* go, int ep, int fast, int lane)
{
    int spins = 0;   // whole wave: 32 flags in 2 cachelines
    if (fast) {
        while (!__all(*(volatile int*)&arrg[lane & 31] >= ep)) {
            __builtin_amdgcn_s_sleep(1);
            if (++spins > (1 << 24)) break;
        }
        __builtin_amdgcn_fence(__ATOMIC_ACQ_REL, "workgroup");   // compiler order only
        if (lane == 0) *(volatile int*)go = ep;
    } else {
        while (!__all(__hip_atomic_load(&arrg[lane & 31], __ATOMIC_RELAXED,
                                        __HIP_MEMORY_SCOPE_AGENT) >= ep)) {
            __builtin_amdgcn_s_sleep(1);
            if (++spins > (1 << 24)) break;
        }
        __builtin_amdgcn_fence(__ATOMIC_ACQUIRE, "agent");
        __builtin_amdgcn_fence(__ATOMIC_RELEASE, "agent");
        if (lane == 0)
            __hip_atomic_store(go, ep, __ATOMIC_RELAXED, __HIP_MEMORY_SCOPE_AGENT);
    }
}
__device__ __forceinline__ void bar_wait(int* go, int ep, int fast)
{
    if (threadIdx.x == 0) {
        int spins = 0;
        if (fast) {
            while (*(volatile int*)go < ep) {
                __builtin_amdgcn_s_sleep(1);
                if (++spins > (1 << 24)) break;
            }
            __builtin_amdgcn_fence(__ATOMIC_ACQUIRE, "workgroup");  // compiler order
        } else {
            while (__hip_atomic_load(go, __ATOMIC_RELAXED, __HIP_MEMORY_SCOPE_AGENT) < ep) {
                __builtin_amdgcn_s_sleep(1);
                if (++spins > (1 << 24)) break;
            }
            __builtin_amdgcn_fence(__ATOMIC_ACQUIRE, "agent");
        }
    }
    __syncthreads();
}

// ---------------------------------------------------------------------------
// K-loop helpers.
// kloop2: plain loads (Ct slot is versioned by t — first-touch per dispatch,
// written before any plain read -> no staleness; weights L2/LDS-resident).
// kloop1a: A operand (RC, rewritten every step) loaded via RELAXED AGENT
// atomic 8B loads — device-scope like the old volatile path (MALL coherence
// point, correct in fast AND fallback modes since no L2 copies ever exist),
// but with NO inter-op ordering -> no per-load s_waitcnt -> all loads stay
// in flight (the old volatile loads were serialized at one vmcnt(0) each,
// ~10 us/phase).
// ---------------------------------------------------------------------------
__device__ __forceinline__ void kloop2(const f16* __restrict__ a0, const f16* __restrict__ a1,
                                       const f16* bp, f32x4& acc0, f32x4& acc1)
{
    f16x8 A0[2][8], A1[2][8], B[2][8];
    #pragma unroll
    for (int i = 0; i < 8; ++i) {
        A0[0][i] = *(const f16x8*)(a0 + i * 32);
        A1[0][i] = *(const f16x8*)(a1 + i * 32);
        B [0][i] = *(const f16x8*)(bp + i * 32);
    }
    #pragma unroll
    for (int h = 0; h < 4; ++h) {
        const int cur = h & 1, nxt = cur ^ 1;
        if (h < 3) {
            #pragma unroll
            for (int i = 0; i < 8; ++i) {
                const int kc = (h + 1) * 8 + i;
                A0[nxt][i] = *(const f16x8*)(a0 + kc * 32);
                A1[nxt][i] = *(const f16x8*)(a1 + kc * 32);
                B [nxt][i] = *(const f16x8*)(bp + kc * 32);
            }
        }
        #pragma unroll
        for (int i = 0; i < 8; ++i) {
            acc0 = MFMA(A0[cur][i], B[cur][i], acc0);
            acc1 = MFMA(A1[cur][i], B[cur][i], acc1);
        }
    }
}
__device__ __forceinline__ void kloop1a(const f16* a, const f16* bp, f32x4& acc)
{
    union Frag { unsigned long long u[2]; f16x8 v; };
    #pragma unroll
    for (int h = 0; h < 4; ++h) {
        Frag A[8]; f16x8 B[8];
        #pragma unroll
        for (int i = 0; i < 8; ++i) {
            const f16* p = a + (h * 8 + i) * 32;
            A[i].u[0] = ALOAD64(p);
            A[i].u[1] = ALOAD64(p + 4);
            B[i] = *(const f16x8*)(bp + (h * 8 + i) * 32);
        }
        #pragma unroll
        for (int i = 0; i < 8; ++i) acc = MFMA(A[i].v, B[i], acc);
    }
}
__device__ __forceinline__ void xpart2(const f16* xa0, const f16* xa1, const f16* bx,
                                       f32x4& acc0, f32x4& acc1)
{
    #pragma unroll
    for (int kc = 0; kc < 10; ++kc) {
        f16x8 B = *(const f16x8*)(bx + kc * 32);
        acc0 = MFMA(*(const f16x8*)(xa0 + kc * 32), B, acc0);
        acc1 = MFMA(*(const f16x8*)(xa1 + kc * 32), B, acc1);
    }
}
__device__ __forceinline__ void xpart1(const f16* xa, const f16* bx, f32x4& acc)
{
    #pragma unroll
    for (int kc = 0; kc < 10; ++kc)
        acc = MFMA(*(const f16x8*)(xa + kc * 32),
                   *(const f16x8*)(bx + kc * 32), acc);
}

// ---------------------------------------------------------------------------
// Persistent recurrence, XCD-pure groups BY CONSTRUCTION. 256 blocks x 256
// thr, cooperative (1 block/CU by LDS; __launch_bounds__(256,1)).
// R5 structure (x-part of global B rows in LDS -> weights L2-resident) +
// relaxed-agent-atomic exchange loads (this round). Register-B variants
// (R1-R3) miscompile — do not re-attempt.
// Group owns batch rows [g*32,+32). Gates: block n-cols [gblk*64,+64), wave
// wv = n-tile (wv<2 LDS, wv>=2 L2-global c-part + LDS x-part). Update: block
// n-cols [gblk*32,+32), wave: m-tile wv&1, n-tile wv>>1.
// ---------------------------------------------------------------------------
__global__ __launch_bounds__(256, 1) void rnn_kernel(
    const f16* __restrict__ xe,  const f16* __restrict__ Wru,
    const f16* __restrict__ Wc,  const f16* __restrict__ Wp,
    const float* __restrict__ bpred, f16* __restrict__ Call,
    float* __restrict__ U, f16* __restrict__ RC,
    int* __restrict__ bar, float* __restrict__ out)
{
    extern __shared__ char smem[];
    f16* ldsRU = (f16*)smem;                    // 32 x LSTR : Wru rows [N0,N0+32)
    f16* ldsC  = ldsRU + 32 * LSTR;             // 16 x LSTR : Wc rows [M0,M0+16)
    f16* ldsX  = ldsC  + 16 * LSTR;             // 48 x LSX  : x-part of global rows
    __shared__ int s_g, s_r, s_fast;

    const int tid  = threadIdx.x;
    const int lane = tid & 63;
    const int wv   = tid >> 6;
    const int q    = lane >> 4;
    const int cx   = lane & 15;
    const int ko   = q * 8;

    // ---- claim rank within actual XCD; one-time fenced grid barrier --------
    if (tid == 0) {
        int xcd = (int)__builtin_amdgcn_s_getreg((31 << 11) | 20) & 15;  // HW_REG_XCC_ID
        int r   = __hip_atomic_fetch_add(&bar[xcd], 1, __ATOMIC_RELAXED,
                                         __HIP_MEMORY_SCOPE_AGENT);
        __builtin_amdgcn_fence(__ATOMIC_RELEASE, "agent");
        __hip_atomic_fetch_add(&bar[16], 1, __ATOMIC_RELAXED, __HIP_MEMORY_SCOPE_AGENT);
        int spins = 0;
        while (__hip_atomic_load(&bar[16], __ATOMIC_RELAXED, __HIP_MEMORY_SCOPE_AGENT) < 256) {
            __builtin_amdgcn_s_sleep(1);
            if (++spins > (1 << 24)) break;
        }
        __builtin_amdgcn_fence(__ATOMIC_ACQUIRE, "agent");
        int ok = 1;
        for (int i = 0; i < 8; ++i) ok &= (bar[i] == BPG);
        if (ok) { s_g = xcd; s_r = r; s_fast = 1; }
        else    { s_g = blockIdx.x & 7; s_r = blockIdx.x >> 3; s_fast = 0; }
    }
    __syncthreads();
    const int g    = s_g;
    const int gblk = s_r;
    const int fast = s_fast;
    const int mG   = g * MPG;
    const int N0   = gblk * 64;
    const int M0   = gblk * 32;
    const int jm   = wv & 1;

    int* arrg = bar + 64 + g * BPG;             // group arrival flags (32 ints)
    int* slot = arrg + gblk;
    int* go   = bar + 384 + g * 16;             // group go flag (padded line)

    // ---- stage LDS weight slices (once) ------------------------------------
    {
        const f16* gRU = Wru + (size_t)N0 * KE;
        for (int i = tid; i < 32 * (KE / 8); i += 256) {
            int r = i / (KE / 8), c = i % (KE / 8);
            *(f16x8*)(ldsRU + r * LSTR + c * 8) = *(const f16x8*)(gRU + (size_t)r * KE + c * 8);
        }
        const f16* gC = Wc + (size_t)M0 * KE;
        for (int i = tid; i < 16 * (KE / 8); i += 256) {
            int r = i / (KE / 8), c = i % (KE / 8);
            *(f16x8*)(ldsC + r * LSTR + c * 8) = *(const f16x8*)(gC + (size_t)r * KE + c * 8);
        }
        // x-part slices for the global-B waves:
        // rows 0..31  = Wru rows [N0+32, N0+64), k in [1024,1344)
        // rows 32..47 = Wc  rows [M0+16, M0+32), k in [1024,1344)
        for (int i = tid; i < 48 * (XP / 8); i += 256) {
            int r = i / (XP / 8), c = i % (XP / 8);
            const f16* src = (r < 32)
                ? (Wru + (size_t)(N0 + 32 + r) * KE + 1024 + c * 8)
                : (Wc  + (size_t)(M0 + 16 + (r - 32)) * KE + 1024 + c * 8);
            *(f16x8*)(ldsX + r * LSX + c * 8) = *(const f16x8*)src;
        }
        __syncthreads();
    }

    // B-fragment pointers. c-part: waves 0,1 LDS, waves 2,3 global (L2).
    // x-part: LDS for ALL waves (waves 0,1 inside LSTR rows; 2,3 in ldsX).
    const f16* bG = (wv < 2) ? (const f16*)(ldsRU + (size_t)(wv * 16 + cx) * LSTR + ko)
                             : (const f16*)(Wru + (size_t)(N0 + wv * 16 + cx) * KE + ko);
    const f16* bU = (wv < 2) ? (const f16*)(ldsC + (size_t)cx * LSTR + ko)
                             : (const f16*)(Wc + (size_t)(M0 + 16 + cx) * KE + ko);
    const f16* bGx = (wv < 2) ? bG + 1024
                              : (const f16*)(ldsX + (size_t)((wv - 2) * 16 + cx) * LSX + ko);
    const f16* bUx = (wv < 2) ? bU + 1024
                              : (const f16*)(ldsX + (size_t)(32 + cx) * LSX + ko);
    const int nG = N0 + wv * 16 + cx;            // gates output column
    const int nU = M0 + (wv >> 1) * 16 + cx;     // update output column
    const int is_chk = (gblk == 0 && wv == 0);

    // ---- prologue: gates x-part for t=0 ------------------------------------
    f32x4 gx0 = {0.f,0.f,0.f,0.f}, gx1 = {0.f,0.f,0.f,0.f};
    xpart2(xe + (size_t)(mG + cx) * XP + ko,
           xe + (size_t)(mG + 16 + cx) * XP + ko, bGx, gx0, gx1);

    int ep = 0;
    for (int t = 0; t < SEQ; ++t) {
        const f16* Ct  = Call + (size_t)t * BATCH * HID;
        f16*       Ct1 = Call + (size_t)(t + 1) * BATCH * HID;
        const f16* xet = xe   + (size_t)t * BATCH * XP;

        // ================= gates phase =================
        {
            // prefetch c for the r-gate epilogue (hides under kloop2)
            float cpf[2][4];
            if (N0 < HID) {
                #pragma unroll
                for (int jt = 0; jt < 2; ++jt)
                    #pragma unroll
                    for (int r = 0; r < 4; ++r)
                        cpf[jt][r] = (float)Ct[(size_t)(mG + jt * 16 + q * 4 + r) * HID + nG];
            }
            f32x4 acc0 = gx0, acc1 = gx1;
            kloop2(Ct + (size_t)(mG + cx) * HID + ko,
                   Ct + (size_t)(mG + 16 + cx) * HID + ko, bG, acc0, acc1);
            if (N0 < HID) {           // r-gate -> RC (volatile store: device-visible)
                #pragma unroll
                for (int jt = 0; jt < 2; ++jt) {
                    const f32x4& ac = jt ? acc1 : acc0;
                    #pragma unroll
                    for (int r = 0; r < 4; ++r) {
                        int m = mG + jt * 16 + q * 4 + r;
                        *(volatile f16*)&RC[(size_t)m * HID + nG] = (f16)(sigm(ac[r]) * cpf[jt][r]);
                    }
                }
            } else {                  // u-gate -> U (relaxed agent atomic store)
                #pragma unroll
                for (int jt = 0; jt < 2; ++jt) {
                    const f32x4& ac = jt ? acc1 : acc0;
                    #pragma unroll
                    for (int r = 0; r < 4; ++r) {
                        int m = mG + jt * 16 + q * 4 + r;
                        __hip_atomic_store(&U[(size_t)m * HID + (nG - HID)], sigm(ac[r]),
                                           __ATOMIC_RELAXED, __HIP_MEMORY_SCOPE_AGENT);
                    }
                }
            }
        }
        ++ep;
        bar_arrive(slot, ep, fast);
        f32x4 ux = {0.f,0.f,0.f,0.f};
        if (is_chk) {                 // checker first: release others ASAP
            bar_check(arrg, go, ep, fast, lane);
            xpart1(xet + (size_t)(mG + jm * 16 + cx) * XP + ko, bUx, ux);
        } else {                      // workers overlap x-part with barrier
            xpart1(xet + (size_t)(mG + jm * 16 + cx) * XP + ko, bUx, ux);
        }
        bar_wait(go, ep, fast);

        // ================= update phase =================
        {
            // prefetch u and c_old before the K-loop (producers published by
            // the barrier just crossed). Relaxed atomic u-loads: pipelined,
            // device-scope.
            float uu[4], cold[4];
            #pragma unroll
            for (int r = 0; r < 4; ++r) {
                int m = mG + jm * 16 + q * 4 + r;
                uu[r]   = __hip_atomic_load(&U[(size_t)m * HID + nU],
                                            __ATOMIC_RELAXED, __HIP_MEMORY_SCOPE_AGENT);
                cold[r] = (float)Ct[(size_t)m * HID + nU];
            }
            f32x4 acc = ux;
            kloop1a(RC + (size_t)(mG + jm * 16 + cx) * HID + ko, bU, acc);
            #pragma unroll
            for (int r = 0; r < 4; ++r) {
                int m = mG + jm * 16 + q * 4 + r;
                float cct = tanhf_(acc[r]);
                *(volatile f16*)&Ct1[(size_t)m * HID + nU] =
                    (f16)(uu[r] * cct + (1.f - uu[r]) * cold[r]);
            }
        }
        ++ep;
        bar_arrive(slot, ep, fast);
        gx0 = (f32x4){0.f,0.f,0.f,0.f};
        gx1 = (f32x4){0.f,0.f,0.f,0.f};
        if (is_chk) {
            bar_check(arrg, go, ep, fast, lane);
            if (t + 1 < SEQ)
                xpart2(xe + (size_t)(t + 1) * BATCH * XP + (size_t)(mG + cx) * XP + ko,
                       xe + (size_t)(t + 1) * BATCH * XP + (size_t)(mG + 16 + cx) * XP + ko,
                       bGx, gx0, gx1);
        } else {
            if (t + 1 < SEQ)
                xpart2(xe + (size_t)(t + 1) * BATCH * XP + (size_t)(mG + cx) * XP + ko,
                       xe + (size_t)(t + 1) * BATCH * XP + (size_t)(mG + 16 + cx) * XP + ko,
                       bGx, gx0, gx1);
        }
        bar_wait(go, ep, fast);
    }

    // ---- prediction (group-local): out[b][t][:] = C[t+1][b][:].Wp^T + bp ---
    #pragma unroll
    for (int i = 0; i < 2; ++i) {
        const int mt = gblk * 8 + wv * 2 + i;    // [0,256) group bt-tile
        const int tt = mt >> 1;
        const int bb = mG + (mt & 1) * 16;
        const f16* ap  = Call + (size_t)(tt + 1) * BATCH * HID + (size_t)(bb + cx) * HID + ko;
        const f16* wp0 = Wp + (size_t)cx * HID + ko;
        const f16* wp1 = Wp + (size_t)(16 + cx) * HID + ko;
        f32x4 acc0 = {0.f,0.f,0.f,0.f}, acc1 = {0.f,0.f,0.f,0.f};
        f16x8 A[8], B0[8], B1[8];
        #pragma unroll
        for (int h = 0; h < 4; ++h) {
            #pragma unroll
            for (int j2 = 0; j2 < 8; ++j2) {
                const int kc = h * 8 + j2;
                A[j2]  = *(const f16x8*)(ap  + kc * 32);
                B0[j2] = *(const f16x8*)(wp0 + kc * 32);
                B1[j2] = *(const f16x8*)(wp1 + kc * 32);
            }
            #pragma unroll
            for (int j2 = 0; j2 < 8; ++j2) {
                acc0 = MFMA(A[j2], B0[j2], acc0);
                acc1 = MFMA(A[j2], B1[j2], acc1);
            }
        }
        #pragma unroll
        for (int nt = 0; nt < 2; ++nt) {
            const int o = nt * 16 + cx;
            if (o < OUTD) {
                const f32x4& ac = nt ? acc1 : acc0;
                #pragma unroll
                for (int r = 0; r < 4; ++r) {
                    const int brow = bb + q * 4 + r;
                    out[((size_t)brow * SEQ + tt) * OUTD + o] = ac[r] + bpred[o];
                }
            }
        }
    }
}

// ---------------------------------------------------------------------------
extern "C" void kernel_launch(void* const* d_in, const int* in_sizes, int n_in,
                              void* d_out, int out_size, void* d_ws, size_t ws_size,
                              hipStream_t stream)
{
    const int*   x   = (const int*)  d_in[0];
    const float* emb = (const float*)d_in[1];
    const float* Wr  = (const float*)d_in[2];
    const float* br  = (const float*)d_in[3];
    const float* Wu  = (const float*)d_in[4];
    const float* bu  = (const float*)d_in[5];
    const float* Wc  = (const float*)d_in[6];
    const float* bc  = (const float*)d_in[7];
    const float* Wp  = (const float*)d_in[8];
    const float* bp  = (const float*)d_in[9];

    // bar region FIRST: [0..16) xcd counts | [16] grid ctr |
    // [64..320) arrival flags | [384..512) go flags (16-int padded)
    char* p = (char*)d_ws;
    int* bar   = (int*)p;  p += 1024 * sizeof(int);
    f16* Wru_e = (f16*)p;  p += (size_t)2048 * KE * 2;
    f16* Wc_e  = (f16*)p;  p += (size_t)1024 * KE * 2;
    f16* Wp_e  = (f16*)p;  p += (size_t)32 * HID * 2;
    f16* xe    = (f16*)p;  p += (size_t)SEQ * BATCH * XP * 2;
    f16* Call  = (f16*)p;  p += (size_t)(SEQ + 1) * BATCH * HID * 2;  // slot 0 = zeros
    float* U   = (float*)p; p += (size_t)BATCH * HID * 4;
    f16* RC    = (f16*)p;  p += (size_t)BATCH * HID * 2;

    const int LDS_BYTES = 48 * LSTR * 2 + 48 * LSX * 2;   // 129,792 + 31,488 = 161,280

    pack_kernel<<<2048, 256, 0, stream>>>(Wr, br, Wu, bu, Wc, bc, Wp, Wru_e, Wc_e, Wp_e);
    gather_kernel<<<4096, 256, 0, stream>>>(x, emb, xe);
    zero_kernel<<<256, 256, 0, stream>>>((uint32_t*)Call, BATCH * HID / 2, (uint32_t*)bar, 1024);

    hipFuncSetAttribute((const void*)rnn_kernel,
                        hipFuncAttributeMaxDynamicSharedMemorySize, LDS_BYTES);

    void* args[] = { &xe, &Wru_e, &Wc_e, &Wp_e, (void*)&bp, &Call, &U, &RC, &bar, &d_out };
    hipLaunchCooperativeKernel((const void*)rnn_kernel, dim3(256), dim3(256),
                               args, LDS_BYTES, stream);
}

// Round 10
// 2999.354 us; speedup vs baseline: 1.2744x; 1.2744x over previous
//
#include <hip/hip_runtime.h>
#include <stdint.h>

typedef _Float16 f16;
typedef _Float16 f16x8 __attribute__((ext_vector_type(8)));
typedef float f32x4 __attribute__((ext_vector_type(4)));

#define BATCH 256
#define SEQ   128
#define EMB   300
#define HID   1024
#define OUTD  20
#define CAT   1324          // HID + EMB
#define KE    1344          // padded K: 1024 (c) + 320 (x incl bias-1, zero pad)
#define XP    320           // xe row: 300 emb + [300]=1.0 + zeros
#define LSTR  1352          // LDS row stride in f16 (full rows, waves 0,1)
#define LSX   328           // LDS x-part row stride in f16 (320 + 8 pad)
#define BPG   32            // blocks per group (== CUs per XCD)
#define MPG   32            // batch rows per group

__device__ __forceinline__ float sigm(float z)  { return 1.f / (1.f + __expf(-z)); }
__device__ __forceinline__ float tanhf_(float z){ float e = __expf(2.f * z); return 1.f - 2.f / (e + 1.f); }

#define MFMA(a,b,c) __builtin_amdgcn_mfma_f32_16x16x32_f16((a),(b),(c),0,0,0)

#define ALOAD64(p) __hip_atomic_load((const unsigned long long*)(p), \
                                     __ATOMIC_RELAXED, __HIP_MEMORY_SCOPE_AGENT)

// ---------------------------------------------------------------------------
// sc0 ("coherent", old glc) memory ops — the XCD-L2 exchange protocol.
// sc0 STORE: write-through to the XCD's shared L2, NO L1 allocation and
// invalidates the local L1 line (classic glc-store semantics). This is the
// fix for R9's bug: plain Ct1 stores left half-stale 128B lines in the
// writer's L1 (lines span two blocks' column ranges).
// sc0 LOAD: bypass L1, read the XCD L2.
// Loads end with one vmcnt(0) (value-ready at exit); stores carry NO wait —
// the __syncthreads() in bar_arrive drains vmcnt before flags publish.
// ---------------------------------------------------------------------------
__device__ __forceinline__ void gld8_sc0(f16x8 (&A)[8], const f16* p)
{
    asm volatile(
        "global_load_dwordx4 %0, %8, off sc0\n\t"
        "global_load_dwordx4 %1, %8, off offset:64 sc0\n\t"
        "global_load_dwordx4 %2, %8, off offset:128 sc0\n\t"
        "global_load_dwordx4 %3, %8, off offset:192 sc0\n\t"
        "global_load_dwordx4 %4, %8, off offset:256 sc0\n\t"
        "global_load_dwordx4 %5, %8, off offset:320 sc0\n\t"
        "global_load_dwordx4 %6, %8, off offset:384 sc0\n\t"
        "global_load_dwordx4 %7, %8, off offset:448 sc0\n\t"
        "s_waitcnt vmcnt(0)"
        : "=&v"(A[0]), "=&v"(A[1]), "=&v"(A[2]), "=&v"(A[3]),
          "=&v"(A[4]), "=&v"(A[5]), "=&v"(A[6]), "=&v"(A[7])
        : "v"(p)
        : "memory");
}
__device__ __forceinline__ void gld4_f32_sc0(float (&r)[4], const float* p0, const float* p1,
                                             const float* p2, const float* p3)
{
    asm volatile(
        "global_load_dword %0, %4, off sc0\n\t"
        "global_load_dword %1, %5, off sc0\n\t"
        "global_load_dword %2, %6, off sc0\n\t"
        "global_load_dword %3, %7, off sc0\n\t"
        "s_waitcnt vmcnt(0)"
        : "=&v"(r[0]), "=&v"(r[1]), "=&v"(r[2]), "=&v"(r[3])
        : "v"(p0), "v"(p1), "v"(p2), "v"(p3)
        : "memory");
}
__device__ __forceinline__ void gst_f16_sc0(f16* p, f16 v)
{
    union { f16 h; unsigned short u; } cv; cv.h = v;
    unsigned int w = cv.u;
    asm volatile("global_store_short %0, %1, off sc0" :: "v"(p), "v"(w) : "memory");
}
__device__ __forceinline__ void gst_f32_sc0(float* p, float v)
{
    asm volatile("global_store_dword %0, %1, off sc0" :: "v"(p), "v"(v) : "memory");
}

// ---------------------------------------------------------------------------
// Weight packing: Wru_e[2048][1344] (rows 0..1023 = W_r|b_r, 1024..2047 = W_u|b_u)
//                 Wc_e[1024][1344], Wp_e[32][1024] (rows >=20 zero)
// ---------------------------------------------------------------------------
__global__ void pack_kernel(const float* __restrict__ Wr, const float* __restrict__ br,
                            const float* __restrict__ Wu, const float* __restrict__ bu,
                            const float* __restrict__ Wc, const float* __restrict__ bc,
                            const float* __restrict__ Wp,
                            f16* __restrict__ Wru_e, f16* __restrict__ Wc_e, f16* __restrict__ Wp_e)
{
    const int NRU = 2048 * KE, NC = 1024 * KE, NP = 32 * HID;
    for (int idx = blockIdx.x * blockDim.x + threadIdx.x; idx < NRU + NC + NP;
         idx += gridDim.x * blockDim.x) {
        if (idx < NRU) {
            int n = idx / KE, k = idx - n * KE;
            const float* Ws = (n < HID) ? Wr : Wu;
            const float* bs = (n < HID) ? br : bu;
            int row = n & (HID - 1);
            float v = (k < CAT) ? Ws[(size_t)row * CAT + k] : ((k == CAT) ? bs[row] : 0.f);
            Wru_e[idx] = (f16)v;
        } else if (idx < NRU + NC) {
            int j = idx - NRU;
            int n = j / KE, k = j - n * KE;
            float v = (k < CAT) ? Wc[(size_t)n * CAT + k] : ((k == CAT) ? bc[n] : 0.f);
            Wc_e[j] = (f16)v;
        } else {
            int j = idx - NRU - NC;
            int n = j / HID, k = j & (HID - 1);
            Wp_e[j] = (n < OUTD) ? (f16)Wp[(size_t)n * HID + k] : (f16)(0.f);
        }
    }
}

// ---------------------------------------------------------------------------
// Embedding gather: xe[t][b][0..319] f16 : emb row, 1.0 at [300], zeros after
// ---------------------------------------------------------------------------
__global__ void gather_kernel(const int* __restrict__ x, const float* __restrict__ emb,
                              f16* __restrict__ xe)
{
    const int TOT = SEQ * BATCH * XP;
    for (int idx = blockIdx.x * blockDim.x + threadIdx.x; idx < TOT;
         idx += gridDim.x * blockDim.x) {
        int e  = idx % XP;
        int rb = idx / XP;            // t*256 + b
        int b  = rb & 255, t = rb >> 8;
        float v;
        if (e < EMB) { int id = x[b * SEQ + t]; v = emb[(size_t)id * EMB + e]; }
        else          v = (e == EMB) ? 1.f : 0.f;
        xe[idx] = (f16)v;
    }
}

__global__ void zero_kernel(uint32_t* __restrict__ c0, int n0, uint32_t* __restrict__ bar, int nb)
{
    for (int i = blockIdx.x * blockDim.x + threadIdx.x; i < n0; i += gridDim.x * blockDim.x)
        c0[i] = 0u;
    if (blockIdx.x == 0)
        for (int i = threadIdx.x; i < nb; i += blockDim.x) bar[i] = 0u;
}

// ---------------------------------------------------------------------------
// Dual-mode relay barrier — PROVEN version restored verbatim (R4/R5/R8
// passing). fast==1: volatile flag stores/polls (device scope; slower than
// L2 but correct and few). R9's plain-store/sc0-poll barrier caused spin
// timeouts — reverted. fast==0: agent atomics + agent fences.
// ---------------------------------------------------------------------------
__device__ __forceinline__ void bar_arrive(int* slot, int ep, int fast)
{
    __syncthreads();
    if (threadIdx.x == 0) {
        if (fast) {
            *(volatile int*)slot = ep;
        } else {
            __builtin_amdgcn_fence(__ATOMIC_RELEASE, "agent");
            __hip_atomic_store(slot, ep, __ATOMIC_RELAXED, __HIP_MEMORY_SCOPE_AGENT);
        }
    }
}
__device__ __forceinline__ void bar_check(int* arrg, int* go, int ep, int fast, int lane)
{
    int spins = 0;   // whole wave: 32 flags in 2 cachelines
    if (fast) {
        while (!__all(*(volatile int*)&arrg[lane & 31] >= ep)) {
            __builtin_amdgcn_s_sleep(1);
            if (++spins > (1 << 24)) break;
        }
        __builtin_amdgcn_fence(__ATOMIC_ACQ_REL, "workgroup");   // compiler order only
        if (lane == 0) *(volatile int*)go = ep;
    } else {
        while (!__all(__hip_atomic_load(&arrg[lane & 31], __ATOMIC_RELAXED,
                                        __HIP_MEMORY_SCOPE_AGENT) >= ep)) {
            __builtin_amdgcn_s_sleep(1);
            if (++spins > (1 << 24)) break;
        }
        __builtin_amdgcn_fence(__ATOMIC_ACQUIRE, "agent");
        __builtin_amdgcn_fence(__ATOMIC_RELEASE, "agent");
        if (lane == 0)
            __hip_atomic_store(go, ep, __ATOMIC_RELAXED, __HIP_MEMORY_SCOPE_AGENT);
    }
}
__device__ __forceinline__ void bar_wait(int* go, int ep, int fast)
{
    if (threadIdx.x == 0) {
        int spins = 0;
        if (fast) {
            while (*(volatile int*)go < ep) {
                __builtin_amdgcn_s_sleep(1);
                if (++spins > (1 << 24)) break;
            }
            __builtin_amdgcn_fence(__ATOMIC_ACQUIRE, "workgroup");  // compiler order
        } else {
            while (__hip_atomic_load(go, __ATOMIC_RELAXED, __HIP_MEMORY_SCOPE_AGENT) < ep) {
                __builtin_amdgcn_s_sleep(1);
                if (++spins > (1 << 24)) break;
            }
            __builtin_amdgcn_fence(__ATOMIC_ACQUIRE, "agent");
        }
    }
    __syncthreads();
}

// ---------------------------------------------------------------------------
// K-loop helpers.
// kloop2 (gates A = Call): PLAIN loads. Sound: Call slots are write-once,
// written by sc0 stores (no L1 allocation anywhere pre-read), consumer's
// first L1 touch is a post-barrier read of fresh L2 data.
// kloop1s (update A = RC, rewritten each step): sc0 batched loads.
// kloop1a: fallback (agent atomics) for non-XCD-pure placement.
// ---------------------------------------------------------------------------
__device__ __forceinline__ void kloop2(const f16* __restrict__ a0, const f16* __restrict__ a1,
                                       const f16* bp, f32x4& acc0, f32x4& acc1)
{
    f16x8 A0[2][8], A1[2][8], B[2][8];
    #pragma unroll
    for (int i = 0; i < 8; ++i) {
        A0[0][i] = *(const f16x8*)(a0 + i * 32);
        A1[0][i] = *(const f16x8*)(a1 + i * 32);
        B [0][i] = *(const f16x8*)(bp + i * 32);
    }
    #pragma unroll
    for (int h = 0; h < 4; ++h) {
        const int cur = h & 1, nxt = cur ^ 1;
        if (h < 3) {
            #pragma unroll
            for (int i = 0; i < 8; ++i) {
                const int kc = (h + 1) * 8 + i;
                A0[nxt][i] = *(const f16x8*)(a0 + kc * 32);
                A1[nxt][i] = *(const f16x8*)(a1 + kc * 32);
                B [nxt][i] = *(const f16x8*)(bp + kc * 32);
            }
        }
        #pragma unroll
        for (int i = 0; i < 8; ++i) {
            acc0 = MFMA(A0[cur][i], B[cur][i], acc0);
            acc1 = MFMA(A1[cur][i], B[cur][i], acc1);
        }
    }
}
__device__ __forceinline__ void kloop1s(const f16* a, const f16* bp, f32x4& acc)
{
    #pragma unroll
    for (int h = 0; h < 4; ++h) {
        f16x8 B[8], A[8];
        #pragma unroll
        for (int i = 0; i < 8; ++i) B[i] = *(const f16x8*)(bp + (h * 8 + i) * 32);
        gld8_sc0(A, a + h * 256);            // 8 x 16B sc0, one L2 RTT
        #pragma unroll
        for (int i = 0; i < 8; ++i) acc = MFMA(A[i], B[i], acc);
    }
}
__device__ __forceinline__ void kloop1a(const f16* a, const f16* bp, f32x4& acc)
{
    union Frag { unsigned long long u[2]; f16x8 v; };
    #pragma unroll
    for (int h = 0; h < 4; ++h) {
        Frag A[8]; f16x8 B[8];
        #pragma unroll
        for (int i = 0; i < 8; ++i) {
            const f16* p = a + (h * 8 + i) * 32;
            A[i].u[0] = ALOAD64(p);
            A[i].u[1] = ALOAD64(p + 4);
            B[i] = *(const f16x8*)(bp + (h * 8 + i) * 32);
        }
        #pragma unroll
        for (int i = 0; i < 8; ++i) acc = MFMA(A[i].v, B[i], acc);
    }
}
__device__ __forceinline__ void xpart2(const f16* xa0, const f16* xa1, const f16* bx,
                                       f32x4& acc0, f32x4& acc1)
{
    #pragma unroll
    for (int kc = 0; kc < 10; ++kc) {
        f16x8 B = *(const f16x8*)(bx + kc * 32);
        acc0 = MFMA(*(const f16x8*)(xa0 + kc * 32), B, acc0);
        acc1 = MFMA(*(const f16x8*)(xa1 + kc * 32), B, acc1);
    }
}
__device__ __forceinline__ void xpart1(const f16* xa, const f16* bx, f32x4& acc)
{
    #pragma unroll
    for (int kc = 0; kc < 10; ++kc)
        acc = MFMA(*(const f16x8*)(xa + kc * 32),
                   *(const f16x8*)(bx + kc * 32), acc);
}

// ---------------------------------------------------------------------------
// Persistent recurrence, XCD-pure groups BY CONSTRUCTION. 256 blocks x 256
// thr, cooperative (1 block/CU by LDS; __launch_bounds__(256,1)).
// THIS ROUND (fix of R9): exchange DATA pinned at XCD-L2 scope with
// sc0 STORES (write-through L2, no L1 alloc — fixes R9's half-line L1
// staleness) + sc0 LOADS for RC/U, PLAIN loads for write-once Call;
// barrier restored to the PROVEN volatile relay (fixes R9's timeouts).
// WRITE_SIZE 267MB (R8) proved the volatile exchange was HBM-level; this
// keeps it in the XCD L2. Register-B variants (R1-R3) miscompile — do not
// re-attempt.
// ---------------------------------------------------------------------------
__global__ __launch_bounds__(256, 1) void rnn_kernel(
    const f16* __restrict__ xe,  const f16* __restrict__ Wru,
    const f16* __restrict__ Wc,  const f16* __restrict__ Wp,
    const float* __restrict__ bpred, f16* __restrict__ Call,
    float* __restrict__ U, f16* __restrict__ RC,
    int* __restrict__ bar, float* __restrict__ out)
{
    extern __shared__ char smem[];
    f16* ldsRU = (f16*)smem;                    // 32 x LSTR : Wru rows [N0,N0+32)
    f16* ldsC  = ldsRU + 32 * LSTR;             // 16 x LSTR : Wc rows [M0,M0+16)
    f16* ldsX  = ldsC  + 16 * LSTR;             // 48 x LSX  : x-part of global rows
    __shared__ int s_g, s_r, s_fast;

    const int tid  = threadIdx.x;
    const int lane = tid & 63;
    const int wv   = tid >> 6;
    const int q    = lane >> 4;
    const int cx   = lane & 15;
    const int ko   = q * 8;

    // ---- claim rank within actual XCD; one-time fenced grid barrier --------
    if (tid == 0) {
        int xcd = (int)__builtin_amdgcn_s_getreg((31 << 11) | 20) & 15;  // HW_REG_XCC_ID
        int r   = __hip_atomic_fetch_add(&bar[xcd], 1, __ATOMIC_RELAXED,
                                         __HIP_MEMORY_SCOPE_AGENT);
        __builtin_amdgcn_fence(__ATOMIC_RELEASE, "agent");
        __hip_atomic_fetch_add(&bar[16], 1, __ATOMIC_RELAXED, __HIP_MEMORY_SCOPE_AGENT);
        int spins = 0;
        while (__hip_atomic_load(&bar[16], __ATOMIC_RELAXED, __HIP_MEMORY_SCOPE_AGENT) < 256) {
            __builtin_amdgcn_s_sleep(1);
            if (++spins > (1 << 24)) break;
        }
        __builtin_amdgcn_fence(__ATOMIC_ACQUIRE, "agent");
        int ok = 1;
        for (int i = 0; i < 8; ++i) ok &= (bar[i] == BPG);
        if (ok) { s_g = xcd; s_r = r; s_fast = 1; }
        else    { s_g = blockIdx.x & 7; s_r = blockIdx.x >> 3; s_fast = 0; }
    }
    __syncthreads();
    const int g    = s_g;
    const int gblk = s_r;
    const int fast = s_fast;
    const int mG   = g * MPG;
    const int N0   = gblk * 64;
    const int M0   = gblk * 32;
    const int jm   = wv & 1;

    int* arrg = bar + 64 + g * BPG;             // group arrival flags (32 ints)
    int* slot = arrg + gblk;
    int* go   = bar + 384 + g * 16;             // group go flag (padded line)

    // ---- stage LDS weight slices (once) ------------------------------------
    {
        const f16* gRU = Wru + (size_t)N0 * KE;
        for (int i = tid; i < 32 * (KE / 8); i += 256) {
            int r = i / (KE / 8), c = i % (KE / 8);
            *(f16x8*)(ldsRU + r * LSTR + c * 8) = *(const f16x8*)(gRU + (size_t)r * KE + c * 8);
        }
        const f16* gC = Wc + (size_t)M0 * KE;
        for (int i = tid; i < 16 * (KE / 8); i += 256) {
            int r = i / (KE / 8), c = i % (KE / 8);
            *(f16x8*)(ldsC + r * LSTR + c * 8) = *(const f16x8*)(gC + (size_t)r * KE + c * 8);
        }
        // x-part slices for the global-B waves:
        // rows 0..31  = Wru rows [N0+32, N0+64), k in [1024,1344)
        // rows 32..47 = Wc  rows [M0+16, M0+32), k in [1024,1344)
        for (int i = tid; i < 48 * (XP / 8); i += 256) {
            int r = i / (XP / 8), c = i % (XP / 8);
            const f16* src = (r < 32)
                ? (Wru + (size_t)(N0 + 32 + r) * KE + 1024 + c * 8)
                : (Wc  + (size_t)(M0 + 16 + (r - 32)) * KE + 1024 + c * 8);
            *(f16x8*)(ldsX + r * LSX + c * 8) = *(const f16x8*)src;
        }
        __syncthreads();
    }

    // B-fragment pointers. c-part: waves 0,1 LDS, waves 2,3 global (L2).
    // x-part: LDS for ALL waves (waves 0,1 inside LSTR rows; 2,3 in ldsX).
    const f16* bG = (wv < 2) ? (const f16*)(ldsRU + (size_t)(wv * 16 + cx) * LSTR + ko)
                             : (const f16*)(Wru + (size_t)(N0 + wv * 16 + cx) * KE + ko);
    const f16* bU = (wv < 2) ? (const f16*)(ldsC + (size_t)cx * LSTR + ko)
                             : (const f16*)(Wc + (size_t)(M0 + 16 + cx) * KE + ko);
    const f16* bGx = (wv < 2) ? bG + 1024
                              : (const f16*)(ldsX + (size_t)((wv - 2) * 16 + cx) * LSX + ko);
    const f16* bUx = (wv < 2) ? bU + 1024
                              : (const f16*)(ldsX + (size_t)(32 + cx) * LSX + ko);
    const int nG = N0 + wv * 16 + cx;            // gates output column
    const int nU = M0 + (wv >> 1) * 16 + cx;     // update output column
    const int is_chk = (gblk == 0 && wv == 0);

    // ---- prologue: gates x-part for t=0 ------------------------------------
    f32x4 gx0 = {0.f,0.f,0.f,0.f}, gx1 = {0.f,0.f,0.f,0.f};
    xpart2(xe + (size_t)(mG + cx) * XP + ko,
           xe + (size_t)(mG + 16 + cx) * XP + ko, bGx, gx0, gx1);

    int ep = 0;
    for (int t = 0; t < SEQ; ++t) {
        const f16* Ct  = Call + (size_t)t * BATCH * HID;
        f16*       Ct1 = Call + (size_t)(t + 1) * BATCH * HID;
        const f16* xet = xe   + (size_t)t * BATCH * XP;

        // ================= gates phase =================
        {
            // prefetch c for the r-gate epilogue (plain: slot immutable since
            // its sc0 write; hides under kloop2)
            float cpf[2][4];
            if (N0 < HID) {
                #pragma unroll
                for (int jt = 0; jt < 2; ++jt)
                    #pragma unroll
                    for (int r = 0; r < 4; ++r)
                        cpf[jt][r] = (float)Ct[(size_t)(mG + jt * 16 + q * 4 + r) * HID + nG];
            }
            f32x4 acc0 = gx0, acc1 = gx1;
            kloop2(Ct + (size_t)(mG + cx) * HID + ko,
                   Ct + (size_t)(mG + 16 + cx) * HID + ko, bG, acc0, acc1);
            if (N0 < HID) {           // r-gate -> RC
                #pragma unroll
                for (int jt = 0; jt < 2; ++jt) {
                    const f32x4& ac = jt ? acc1 : acc0;
                    #pragma unroll
                    for (int r = 0; r < 4; ++r) {
                        int m = mG + jt * 16 + q * 4 + r;
                        f16 vv = (f16)(sigm(ac[r]) * cpf[jt][r]);
                        if (fast) gst_f16_sc0(&RC[(size_t)m * HID + nG], vv);  // sc0 -> L2
                        else      *(volatile f16*)&RC[(size_t)m * HID + nG] = vv;
                    }
                }
            } else {                  // u-gate -> U
                #pragma unroll
                for (int jt = 0; jt < 2; ++jt) {
                    const f32x4& ac = jt ? acc1 : acc0;
                    #pragma unroll
                    for (int r = 0; r < 4; ++r) {
                        int m = mG + jt * 16 + q * 4 + r;
                        float uv = sigm(ac[r]);
                        if (fast) gst_f32_sc0(&U[(size_t)m * HID + (nG - HID)], uv); // sc0
                        else __hip_atomic_store(&U[(size_t)m * HID + (nG - HID)], uv,
                                                __ATOMIC_RELAXED, __HIP_MEMORY_SCOPE_AGENT);
                    }
                }
            }
        }
        ++ep;
        bar_arrive(slot, ep, fast);      // __syncthreads drains sc0 stores to L2
        f32x4 ux = {0.f,0.f,0.f,0.f};
        if (is_chk) {                 // checker first: release others ASAP
            bar_check(arrg, go, ep, fast, lane);
            xpart1(xet + (size_t)(mG + jm * 16 + cx) * XP + ko, bUx, ux);
        } else {                      // workers overlap x-part with barrier
            xpart1(xet + (size_t)(mG + jm * 16 + cx) * XP + ko, bUx, ux);
        }
        bar_wait(go, ep, fast);

        // ================= update phase =================
        {
            // u (rewritten every step -> sc0) and c_old (immutable -> plain)
            float uu[4], cold[4];
            {
                int m0 = mG + jm * 16 + q * 4;
                if (fast) {
                    gld4_f32_sc0(uu, &U[(size_t)m0 * HID + nU],
                                     &U[(size_t)(m0 + 1) * HID + nU],
                                     &U[(size_t)(m0 + 2) * HID + nU],
                                     &U[(size_t)(m0 + 3) * HID + nU]);
                } else {
                    #pragma unroll
                    for (int r = 0; r < 4; ++r)
                        uu[r] = __hip_atomic_load(&U[(size_t)(m0 + r) * HID + nU],
                                                  __ATOMIC_RELAXED, __HIP_MEMORY_SCOPE_AGENT);
                }
                #pragma unroll
                for (int r = 0; r < 4; ++r)
                    cold[r] = (float)Ct[(size_t)(m0 + r) * HID + nU];
            }
            f32x4 acc = ux;
            const f16* a = RC + (size_t)(mG + jm * 16 + cx) * HID + ko;
            if (fast) kloop1s(a, bU, acc);
            else      kloop1a(a, bU, acc);
            #pragma unroll
            for (int r = 0; r < 4; ++r) {
                int m = mG + jm * 16 + q * 4 + r;
                float cct = tanhf_(acc[r]);
                f16 cv = (f16)(uu[r] * cct + (1.f - uu[r]) * cold[r]);
                if (fast) gst_f16_sc0(&Ct1[(size_t)m * HID + nU], cv);         // sc0 -> L2
                else      *(volatile f16*)&Ct1[(size_t)m * HID + nU] = cv;
            }
        }
        ++ep;
        bar_arrive(slot, ep, fast);
        gx0 = (f32x4){0.f,0.f,0.f,0.f};
        gx1 = (f32x4){0.f,0.f,0.f,0.f};
        if (is_chk) {
            bar_check(arrg, go, ep, fast, lane);
            if (t + 1 < SEQ)
                xpart2(xe + (size_t)(t + 1) * BATCH * XP + (size_t)(mG + cx) * XP + ko,
                       xe + (size_t)(t + 1) * BATCH * XP + (size_t)(mG + 16 + cx) * XP + ko,
                       bGx, gx0, gx1);
        } else {
            if (t + 1 < SEQ)
                xpart2(xe + (size_t)(t + 1) * BATCH * XP + (size_t)(mG + cx) * XP + ko,
                       xe + (size_t)(t + 1) * BATCH * XP + (size_t)(mG + 16 + cx) * XP + ko,
                       bGx, gx0, gx1);
        }
        bar_wait(go, ep, fast);
    }

    // ---- prediction (group-local): out[b][t][:] = C[t+1][b][:].Wp^T + bp ---
    // plain loads: Call slots are final; sc0 writes never left stale L1
    // copies, and any L1 lines this CU holds were read post-write.
    #pragma unroll
    for (int i = 0; i < 2; ++i) {
        const int mt = gblk * 8 + wv * 2 + i;    // [0,256) group bt-tile
        const int tt = mt >> 1;
        const int bb = mG + (mt & 1) * 16;
        const f16* ap  = Call + (size_t)(tt + 1) * BATCH * HID + (size_t)(bb + cx) * HID + ko;
        const f16* wp0 = Wp + (size_t)cx * HID + ko;
        const f16* wp1 = Wp + (size_t)(16 + cx) * HID + ko;
        f32x4 acc0 = {0.f,0.f,0.f,0.f}, acc1 = {0.f,0.f,0.f,0.f};
        f16x8 A[8], B0[8], B1[8];
        #pragma unroll
        for (int h = 0; h < 4; ++h) {
            #pragma unroll
            for (int j2 = 0; j2 < 8; ++j2) {
                const int kc = h * 8 + j2;
                A[j2]  = *(const f16x8*)(ap  + kc * 32);
                B0[j2] = *(const f16x8*)(wp0 + kc * 32);
                B1[j2] = *(const f16x8*)(wp1 + kc * 32);
            }
            #pragma unroll
            for (int j2 = 0; j2 < 8; ++j2) {
                acc0 = MFMA(A[j2], B0[j2], acc0);
                acc1 = MFMA(A[j2], B1[j2], acc1);
            }
        }
        #pragma unroll
        for (int nt = 0; nt < 2; ++nt) {
            const int o = nt * 16 + cx;
            if (o < OUTD) {
                const f32x4& ac = nt ? acc1 : acc0;
                #pragma unroll
                for (int r = 0; r < 4; ++r) {
                    const int brow = bb + q * 4 + r;
                    out[((size_t)brow * SEQ + tt) * OUTD + o] = ac[r] + bpred[o];
                }
            }
        }
    }
}

// ---------------------------------------------------------------------------
extern "C" void kernel_launch(void* const* d_in, const int* in_sizes, int n_in,
                              void* d_out, int out_size, void* d_ws, size_t ws_size,
                              hipStream_t stream)
{
    const int*   x   = (const int*)  d_in[0];
    const float* emb = (const float*)d_in[1];
    const float* Wr  = (const float*)d_in[2];
    const float* br  = (const float*)d_in[3];
    const float* Wu  = (const float*)d_in[4];
    const float* bu  = (const float*)d_in[5];
    const float* Wc  = (const float*)d_in[6];
    const float* bc  = (const float*)d_in[7];
    const float* Wp  = (const float*)d_in[8];
    const float* bp  = (const float*)d_in[9];

    // bar region FIRST: [0..16) xcd counts | [16] grid ctr |
    // [64..320) arrival flags | [384..512) go flags (16-int padded)
    char* p = (char*)d_ws;
    int* bar   = (int*)p;  p += 1024 * sizeof(int);
    f16* Wru_e = (f16*)p;  p += (size_t)2048 * KE * 2;
    f16* Wc_e  = (f16*)p;  p += (size_t)1024 * KE * 2;
    f16* Wp_e  = (f16*)p;  p += (size_t)32 * HID * 2;
    f16* xe    = (f16*)p;  p += (size_t)SEQ * BATCH * XP * 2;
    f16* Call  = (f16*)p;  p += (size_t)(SEQ + 1) * BATCH * HID * 2;  // slot 0 = zeros
    float* U   = (float*)p; p += (size_t)BATCH * HID * 4;
    f16* RC    = (f16*)p;  p += (size_t)BATCH * HID * 2;

    const int LDS_BYTES = 48 * LSTR * 2 + 48 * LSX * 2;   // 129,792 + 31,488 = 161,280

    pack_kernel<<<2048, 256, 0, stream>>>(Wr, br, Wu, bu, Wc, bc, Wp, Wru_e, Wc_e, Wp_e);
    gather_kernel<<<4096, 256, 0, stream>>>(x, emb, xe);
    zero_kernel<<<256, 256, 0, stream>>>((uint32_t*)Call, BATCH * HID / 2, (uint32_t*)bar, 1024);

    hipFuncSetAttribute((const void*)rnn_kernel,
                        hipFuncAttributeMaxDynamicSharedMemorySize, LDS_BYTES);

    void* args[] = { &xe, &Wru_e, &Wc_e, &Wp_e, (void*)&bp, &Call, &U, &RC, &bar, &d_out };
    hipLaunchCooperativeKernel((const void*)rnn_kernel, dim3(256), dim3(256),
                               args, LDS_BYTES, stream);
}